// Round 1
// baseline (2063.495 us; speedup 1.0000x reference)
//
#include <hip/hip_runtime.h>
#include <stdint.h>

#define N_EXP  2048
#define N_DICT 65536
#define N_PIX  1600
#define TOPK   10
#define NCHUNK 8
#define CHUNK  8192   // N_DICT / NCHUNK
#define K1     16     // per-chunk candidates kept per row
#define KTH    8      // per-thread top list in merge kernel
#define K2     16     // refine set size

#define BM 128
#define BN 128
#define BK 64
#define KTILES (N_PIX / BK)   // 25

typedef __attribute__((ext_vector_type(8))) __bf16 bf16x8;
typedef __attribute__((ext_vector_type(4))) float  f32x4;

// float -> bf16 (RNE)
__device__ __forceinline__ unsigned short f2bf(float f) {
    unsigned int u = __float_as_uint(f);
    unsigned int r = (u + 0x7FFFu + ((u >> 16) & 1u)) >> 16;
    return (unsigned short)r;
}

__device__ __forceinline__ float blockReduceSumF(float v) {
    __shared__ float p[4];
    #pragma unroll
    for (int o = 32; o > 0; o >>= 1) v += __shfl_down(v, o);
    __syncthreads();
    if ((threadIdx.x & 63) == 0) p[threadIdx.x >> 6] = v;
    __syncthreads();
    return p[0] + p[1] + p[2] + p[3];
}

// ---------------- prep: mean-subtract + normalize -> bf16 ----------------
__global__ __launch_bounds__(256) void prep_rows(const float* __restrict__ in,
                                                 unsigned short* __restrict__ outb) {
    const int row = blockIdx.x;
    const int tid = threadIdx.x;
    const float* x = in + (size_t)row * N_PIX;
    float v[7];
    float s = 0.f;
    #pragma unroll
    for (int it = 0; it < 7; ++it) {
        int j = tid + it * 256;
        float t = (j < N_PIX) ? x[j] : 0.f;
        v[it] = t; s += t;
    }
    s = blockReduceSumF(s);
    const float mean = s * (1.0f / N_PIX);
    float ss = 0.f;
    #pragma unroll
    for (int it = 0; it < 7; ++it) {
        int j = tid + it * 256;
        float c = v[it] - mean;
        if (j < N_PIX) ss += c * c;
    }
    ss = blockReduceSumF(ss);
    const float rn = rsqrtf(ss);
    unsigned short* o = outb + (size_t)row * N_PIX;
    #pragma unroll
    for (int it = 0; it < 7; ++it) {
        int j = tid + it * 256;
        if (j < N_PIX) o[j] = f2bf((v[it] - mean) * rn);
    }
}

// ---------------- bf16 GEMM: C[m][n] = sum_k Q[m][k] * D[n][k] ----------------
__global__ __launch_bounds__(256) void gemm_bt(const unsigned short* __restrict__ A,
                                               const unsigned short* __restrict__ B,
                                               float* __restrict__ C) {
    __shared__ __attribute__((aligned(16))) unsigned short As[BM * BK];
    __shared__ __attribute__((aligned(16))) unsigned short Bs[BN * BK];
    const int tid  = threadIdx.x;
    const int lane = tid & 63;
    const int w    = tid >> 6;
    const int wm   = w >> 1, wn = w & 1;
    const int bm   = blockIdx.y, bn = blockIdx.x;
    const unsigned short* Ag = A + (size_t)bm * BM * N_PIX;
    const unsigned short* Bg = B + (size_t)bn * BN * N_PIX;

    const int ldr = lane >> 3;         // row within 8-row chunk
    const int ldc = (lane & 7) * 8;    // col element within tile row
    const int m    = lane & 15;
    const int quad = lane >> 4;

    f32x4 acc[4][4];
    #pragma unroll
    for (int i = 0; i < 4; ++i)
        #pragma unroll
        for (int j = 0; j < 4; ++j)
            acc[i][j] = (f32x4){0.f, 0.f, 0.f, 0.f};

    for (int kt = 0; kt < KTILES; ++kt) {
        const int k0 = kt * BK;
        #pragma unroll
        for (int t = 0; t < 4; ++t) {
            int r = w * 32 + t * 8 + ldr;
            __builtin_amdgcn_global_load_lds(
                (const __attribute__((address_space(1))) void*)(const void*)(Ag + (size_t)r * N_PIX + k0 + ldc),
                (__attribute__((address_space(3))) void*)(void*)((char*)As + (w * 4 + t) * 1024),
                16, 0, 0);
            __builtin_amdgcn_global_load_lds(
                (const __attribute__((address_space(1))) void*)(const void*)(Bg + (size_t)r * N_PIX + k0 + ldc),
                (__attribute__((address_space(3))) void*)(void*)((char*)Bs + (w * 4 + t) * 1024),
                16, 0, 0);
        }
        __syncthreads();
        #pragma unroll
        for (int ks = 0; ks < BK; ks += 32) {
            bf16x8 af[4], bfr[4];
            #pragma unroll
            for (int i = 0; i < 4; ++i)
                af[i] = *(const bf16x8*)(&As[(wm * 64 + i * 16 + m) * BK + ks + quad * 8]);
            #pragma unroll
            for (int j = 0; j < 4; ++j)
                bfr[j] = *(const bf16x8*)(&Bs[(wn * 64 + j * 16 + m) * BK + ks + quad * 8]);
            #pragma unroll
            for (int i = 0; i < 4; ++i)
                #pragma unroll
                for (int j = 0; j < 4; ++j)
                    acc[i][j] = __builtin_amdgcn_mfma_f32_16x16x32_bf16(af[i], bfr[j], acc[i][j], 0, 0, 0);
        }
        __syncthreads();
    }

    // epilogue: D layout col = lane&15, row = quad*4 + reg
    #pragma unroll
    for (int i = 0; i < 4; ++i) {
        int rbase = bm * BM + wm * 64 + i * 16 + quad * 4;
        #pragma unroll
        for (int j = 0; j < 4; ++j) {
            int col = bn * BN + wn * 64 + j * 16 + m;
            #pragma unroll
            for (int r = 0; r < 4; ++r)
                C[(size_t)(rbase + r) * CHUNK + col] = acc[i][j][r];
        }
    }
}

// ---------------- per-chunk per-row top-K1 ----------------
__global__ __launch_bounds__(256) void merge_topk(const float* __restrict__ S,
                                                  float* __restrict__ cand_s,
                                                  int* __restrict__ cand_i,
                                                  int chunk) {
    __shared__ float Ms[256 * K1];
    __shared__ int   Mi[256 * K1];
    const int row = blockIdx.x, tid = threadIdx.x;
    const float* s = S + (size_t)row * CHUNK;

    float ls[KTH]; int li[KTH];
    #pragma unroll
    for (int t = 0; t < KTH; ++t) { ls[t] = -2.f; li[t] = 0; }
    #pragma unroll
    for (int it = 0; it < CHUNK / 256; ++it) {
        int j = tid + it * 256;
        float v = s[j];
        if (v > ls[KTH - 1]) {
            float cv = v; int ci = j;
            #pragma unroll
            for (int t = 0; t < KTH; ++t) {
                bool sw = cv > ls[t];
                float ts = ls[t]; int ti = li[t];
                ls[t] = sw ? cv : ts; li[t] = sw ? ci : ti;
                cv = sw ? ts : cv;   ci = sw ? ti : ci;
            }
        }
    }
    #pragma unroll
    for (int t = 0; t < KTH; ++t) { Ms[tid * K1 + t] = ls[t]; Mi[tid * K1 + t] = li[t]; }
    #pragma unroll
    for (int t = KTH; t < K1; ++t) { Ms[tid * K1 + t] = -3.f; Mi[tid * K1 + t] = 0; }
    __syncthreads();

    #pragma unroll
    for (int lev = 0; lev < 8; ++lev) {
        int stride = 1 << lev;
        if ((tid & (2 * stride - 1)) == 0) {
            int ia = tid * K1, ib = (tid + stride) * K1;
            float rs[K1]; int ri[K1];
            int pa = 0, pb = 0;
            #pragma unroll
            for (int t = 0; t < K1; ++t) {
                float va = Ms[ia + pa], vb = Ms[ib + pb];
                bool ta = (va >= vb);
                rs[t] = ta ? va : vb;
                ri[t] = ta ? Mi[ia + pa] : Mi[ib + pb];
                pa += ta ? 1 : 0; pb += ta ? 0 : 1;
            }
            #pragma unroll
            for (int t = 0; t < K1; ++t) { Ms[ia + t] = rs[t]; Mi[ia + t] = ri[t]; }
        }
        __syncthreads();
    }
    if (tid < K1) {
        cand_s[(size_t)row * (NCHUNK * K1) + chunk * K1 + tid] = Ms[tid];
        cand_i[(size_t)row * (NCHUNK * K1) + chunk * K1 + tid] = chunk * CHUNK + Mi[tid];
    }
}

// ---------------- fp64 rescoring of K2 candidates + outputs ----------------
__global__ __launch_bounds__(256) void refine_out(const float* __restrict__ expd,
                                                  const float* __restrict__ pat,
                                                  const float* __restrict__ so3,
                                                  const float* __restrict__ cand_s,
                                                  const int* __restrict__ cand_i,
                                                  float* __restrict__ out) {
    __shared__ double qc[N_PIX];
    __shared__ double pd[4], pd2[4], pd3[4];
    __shared__ int    sel[K2];
    __shared__ double cosv[K2];
    const int row = blockIdx.x, tid = threadIdx.x;
    const float* x = expd + (size_t)row * N_PIX;

    double s1 = 0.0;
    for (int j = tid; j < N_PIX; j += 256) s1 += (double)x[j];
    #pragma unroll
    for (int o = 32; o > 0; o >>= 1) s1 += __shfl_down(s1, o);
    if ((tid & 63) == 0) pd[tid >> 6] = s1;
    __syncthreads();
    const double mean = (pd[0] + pd[1] + pd[2] + pd[3]) * (1.0 / N_PIX);

    double s2 = 0.0, sc = 0.0;
    for (int j = tid; j < N_PIX; j += 256) {
        double c = (double)x[j] - mean;
        qc[j] = c; s2 += c * c; sc += c;
    }
    #pragma unroll
    for (int o = 32; o > 0; o >>= 1) { s2 += __shfl_down(s2, o); sc += __shfl_down(sc, o); }
    if ((tid & 63) == 0) { pd2[tid >> 6] = s2; pd3[tid >> 6] = sc; }
    __syncthreads();
    const double sumsq = pd2[0] + pd2[1] + pd2[2] + pd2[3];
    const double sqc   = pd3[0] + pd3[1] + pd3[2] + pd3[3];
    const double invq  = 1.0 / sqrt(sumsq);

    // select top-K2 candidates (by bf16 score) from the NCHUNK*K1 pool
    if (tid == 0) {
        float bs[K2]; int bi[K2];
        #pragma unroll
        for (int t = 0; t < K2; ++t) { bs[t] = -3.f; bi[t] = 0; }
        for (int c = 0; c < NCHUNK * K1; ++c) {
            float v = cand_s[(size_t)row * (NCHUNK * K1) + c];
            int  ix = cand_i[(size_t)row * (NCHUNK * K1) + c];
            if (v > bs[K2 - 1]) {
                float cv = v; int ci = ix;
                #pragma unroll
                for (int t = 0; t < K2; ++t) {
                    bool sw = cv > bs[t];
                    float ts = bs[t]; int ti = bi[t];
                    bs[t] = sw ? cv : ts; bi[t] = sw ? ci : ti;
                    cv = sw ? ts : cv;   ci = sw ? ti : ci;
                }
            }
        }
        #pragma unroll
        for (int t = 0; t < K2; ++t) sel[t] = bi[t];
    }
    __syncthreads();

    // fp64 exact cos for each selected candidate: 16 threads per candidate
    const int c  = tid >> 4;
    const int sl = tid & 15;
    const int di = sel[c];
    const float* p = pat + (size_t)di * N_PIX;
    double sp = 0.0, spp = 0.0, sqp = 0.0;
    for (int j = sl; j < N_PIX; j += 16) {
        double pv = (double)p[j];
        sp += pv; spp += pv * pv; sqp += qc[j] * pv;
    }
    #pragma unroll
    for (int o = 8; o > 0; o >>= 1) {
        sp  += __shfl_down(sp,  o, 16);
        spp += __shfl_down(spp, o, 16);
        sqp += __shfl_down(sqp, o, 16);
    }
    if (sl == 0) {
        double mp   = sp * (1.0 / N_PIX);
        double varp = spp - sp * sp * (1.0 / N_PIX);
        double invd = 1.0 / sqrt(varp);
        cosv[c] = (sqp - mp * sqc) * invq * invd;
    }
    __syncthreads();

    if (tid == 0) {
        double cv[K2]; int ci[K2];
        for (int t = 0; t < K2; ++t) { cv[t] = cosv[t]; ci[t] = sel[t]; }
        for (int a = 1; a < K2; ++a) {
            double kv = cv[a]; int ki = ci[a];
            int b = a - 1;
            while (b >= 0 && (cv[b] < kv || (cv[b] == kv && ci[b] > ki))) {
                cv[b + 1] = cv[b]; ci[b + 1] = ci[b]; --b;
            }
            cv[b + 1] = kv; ci[b + 1] = ki;
        }
        float* oa = out;
        float* oi = out + (size_t)N_EXP * TOPK;
        float* oo = out + (size_t)2 * N_EXP * TOPK;
        for (int r = 0; r < TOPK; ++r) {
            double cc = cv[r];
            if (cc > 1.0) cc = 1.0;
            if (cc < -1.0) cc = -1.0;
            oa[(size_t)row * TOPK + r] = (float)acos(cc);
            oi[(size_t)row * TOPK + r] = (float)ci[r];
            int q4 = ci[r];
            #pragma unroll
            for (int t = 0; t < 4; ++t)
                oo[((size_t)row * TOPK + r) * 4 + t] = so3[(size_t)q4 * 4 + t];
        }
    }
}

extern "C" void kernel_launch(void* const* d_in, const int* in_sizes, int n_in,
                              void* d_out, int out_size, void* d_ws, size_t ws_size,
                              hipStream_t stream) {
    const float* expd = (const float*)d_in[0];
    const float* pat  = (const float*)d_in[1];
    const float* so3  = (const float*)d_in[2];
    float* out = (float*)d_out;
    char* ws = (char*)d_ws;

    const size_t QB = (size_t)N_EXP  * N_PIX * 2;   //   6.6 MB bf16 queries
    const size_t DB = (size_t)N_DICT * N_PIX * 2;   // 209.7 MB bf16 dict
    const size_t SB = (size_t)N_EXP  * CHUNK * 4;   //  67.1 MB score chunk
    const size_t CS = (size_t)N_EXP  * NCHUNK * K1 * 4;

    unsigned short* Qb = (unsigned short*)ws;
    unsigned short* Db = (unsigned short*)(ws + QB);
    float* S  = (float*)(ws + QB + DB);
    float* cs = (float*)(ws + QB + DB + SB);
    int*   ci = (int*)  (ws + QB + DB + SB + CS);

    prep_rows<<<N_EXP, 256, 0, stream>>>(expd, Qb);
    prep_rows<<<N_DICT, 256, 0, stream>>>(pat, Db);
    for (int c = 0; c < NCHUNK; ++c) {
        gemm_bt<<<dim3(CHUNK / BN, N_EXP / BM), 256, 0, stream>>>(
            Qb, Db + (size_t)c * CHUNK * N_PIX, S);
        merge_topk<<<N_EXP, 256, 0, stream>>>(S, cs, ci, c);
    }
    refine_out<<<N_EXP, 256, 0, stream>>>(expd, pat, so3, cs, ci, out);
}

// Round 2
// 1543.612 us; speedup vs baseline: 1.3368x; 1.3368x over previous
//
#include <hip/hip_runtime.h>
#include <stdint.h>

#define N_EXP  2048
#define N_DICT 65536
#define N_PIX  1600
#define TOPK   10
#define K1     16     // merged candidate list per row
#define KTH    8      // per-thread top list in merge kernel
#define K2     16     // refine set size
#define NBLK   512    // N_DICT / BN
#define NCAND  (NBLK * 4)   // candidates per row from gemm epilogue

#define BM 128
#define BN 128
#define BK 64
#define KTILES (N_PIX / BK)   // 25

typedef __attribute__((ext_vector_type(8))) __bf16 bf16x8;
typedef __attribute__((ext_vector_type(4))) float  f32x4;

// float -> bf16 (RNE)
__device__ __forceinline__ unsigned short f2bf(float f) {
    unsigned int u = __float_as_uint(f);
    unsigned int r = (u + 0x7FFFu + ((u >> 16) & 1u)) >> 16;
    return (unsigned short)r;
}

__device__ __forceinline__ float sel4f(const float a[4], int p) {
    return p == 0 ? a[0] : (p == 1 ? a[1] : (p == 2 ? a[2] : a[3]));
}
__device__ __forceinline__ int sel4i(const int a[4], int p) {
    return p == 0 ? a[0] : (p == 1 ? a[1] : (p == 2 ? a[2] : a[3]));
}

__device__ __forceinline__ float blockReduceSumF(float v) {
    __shared__ float p[4];
    #pragma unroll
    for (int o = 32; o > 0; o >>= 1) v += __shfl_down(v, o);
    __syncthreads();
    if ((threadIdx.x & 63) == 0) p[threadIdx.x >> 6] = v;
    __syncthreads();
    return p[0] + p[1] + p[2] + p[3];
}

// ---------------- prep: mean-subtract + normalize -> bf16 ----------------
__global__ __launch_bounds__(256) void prep_rows(const float* __restrict__ in,
                                                 unsigned short* __restrict__ outb) {
    const int row = blockIdx.x;
    const int tid = threadIdx.x;
    const float* x = in + (size_t)row * N_PIX;
    float v[7];
    float s = 0.f;
    #pragma unroll
    for (int it = 0; it < 7; ++it) {
        int j = tid + it * 256;
        float t = (j < N_PIX) ? x[j] : 0.f;
        v[it] = t; s += t;
    }
    s = blockReduceSumF(s);
    const float mean = s * (1.0f / N_PIX);
    float ss = 0.f;
    #pragma unroll
    for (int it = 0; it < 7; ++it) {
        int j = tid + it * 256;
        float c = v[it] - mean;
        if (j < N_PIX) ss += c * c;
    }
    ss = blockReduceSumF(ss);
    const float rn = rsqrtf(ss);
    unsigned short* o = outb + (size_t)row * N_PIX;
    #pragma unroll
    for (int it = 0; it < 7; ++it) {
        int j = tid + it * 256;
        if (j < N_PIX) o[j] = f2bf((v[it] - mean) * rn);
    }
}

// ---- bf16 GEMM with fused per-row top-4 epilogue ----
// C[m][n] = sum_k Q[m][k] * D[n][k]; per (row, 128-col block): top-4 -> cand arrays
__global__ __launch_bounds__(256) void gemm_topk(const unsigned short* __restrict__ A,
                                                 const unsigned short* __restrict__ B,
                                                 float* __restrict__ cand_s,
                                                 int* __restrict__ cand_i) {
    __shared__ __attribute__((aligned(16))) char smem[32768];
    unsigned short* As = (unsigned short*)smem;            // 16 KB: 128 x 64 bf16
    unsigned short* Bs = (unsigned short*)(smem + 16384);  // 16 KB: 128 x 64 bf16
    float*          Ss = (float*)smem;                     // epilogue reuse: 64 x 128 f32

    const int tid  = threadIdx.x;
    const int lane = tid & 63;
    const int w    = tid >> 6;
    const int wm   = w >> 1, wn = w & 1;
    const int bm   = blockIdx.x;   // M fastest: consecutive blocks share B tile
    const int bn   = blockIdx.y;
    const unsigned short* Ag = A + (size_t)bm * BM * N_PIX;
    const unsigned short* Bg = B + (size_t)bn * BN * N_PIX;

    const int ldr = lane >> 3;         // row within 8-row chunk
    const int ldc = (lane & 7) * 8;    // col element within tile row
    const int m    = lane & 15;
    const int quad = lane >> 4;

    f32x4 acc[4][4];
    #pragma unroll
    for (int i = 0; i < 4; ++i)
        #pragma unroll
        for (int j = 0; j < 4; ++j)
            acc[i][j] = (f32x4){0.f, 0.f, 0.f, 0.f};

    for (int kt = 0; kt < KTILES; ++kt) {
        const int k0 = kt * BK;
        #pragma unroll
        for (int t = 0; t < 4; ++t) {
            int r = w * 32 + t * 8 + ldr;
            __builtin_amdgcn_global_load_lds(
                (const __attribute__((address_space(1))) void*)(const void*)(Ag + (size_t)r * N_PIX + k0 + ldc),
                (__attribute__((address_space(3))) void*)(void*)((char*)As + (w * 4 + t) * 1024),
                16, 0, 0);
            __builtin_amdgcn_global_load_lds(
                (const __attribute__((address_space(1))) void*)(const void*)(Bg + (size_t)r * N_PIX + k0 + ldc),
                (__attribute__((address_space(3))) void*)(void*)((char*)Bs + (w * 4 + t) * 1024),
                16, 0, 0);
        }
        __syncthreads();
        #pragma unroll
        for (int ks = 0; ks < BK; ks += 32) {
            bf16x8 af[4], bfr[4];
            #pragma unroll
            for (int i = 0; i < 4; ++i)
                af[i] = *(const bf16x8*)(&As[(wm * 64 + i * 16 + m) * BK + ks + quad * 8]);
            #pragma unroll
            for (int j = 0; j < 4; ++j)
                bfr[j] = *(const bf16x8*)(&Bs[(wn * 64 + j * 16 + m) * BK + ks + quad * 8]);
            #pragma unroll
            for (int i = 0; i < 4; ++i)
                #pragma unroll
                for (int j = 0; j < 4; ++j)
                    acc[i][j] = __builtin_amdgcn_mfma_f32_16x16x32_bf16(af[i], bfr[j], acc[i][j], 0, 0, 0);
        }
        __syncthreads();
    }

    // --- fused epilogue: per-row top-4 of this block's 128 cols ---
    // D layout: col = wn*64 + j*16 + m; row = wm*64 + i*16 + quad*4 + r
    const int row4 = tid >> 2;   // 0..63 (row within current half)
    const int part = tid & 3;    // quarter of the 128 cols

    #pragma unroll
    for (int half = 0; half < 2; ++half) {
        __syncthreads();
        if (wm == half) {
            #pragma unroll
            for (int i = 0; i < 4; ++i)
                #pragma unroll
                for (int r = 0; r < 4; ++r) {
                    int row = i * 16 + quad * 4 + r;       // 0..63
                    #pragma unroll
                    for (int j = 0; j < 4; ++j) {
                        int col = wn * 64 + j * 16 + m;
                        Ss[row * 128 + ((col + row) & 127)] = acc[i][j][r];
                    }
                }
        }
        __syncthreads();
        float bs4[4]; int bi4[4];
        bs4[0] = bs4[1] = bs4[2] = bs4[3] = -2.0f;
        bi4[0] = bi4[1] = bi4[2] = bi4[3] = 0;
        #pragma unroll
        for (int k = 0; k < 32; ++k) {
            int col = part * 32 + ((k + 8 * part) & 31);
            float v = Ss[row4 * 128 + ((col + row4) & 127)];
            if (v > bs4[3]) {
                int cix = bn * 128 + col;
                #pragma unroll
                for (int t = 0; t < 4; ++t) {
                    bool sw = v > bs4[t];
                    float ts = bs4[t]; int ti = bi4[t];
                    bs4[t] = sw ? v : ts;  bi4[t] = sw ? cix : ti;
                    v = sw ? ts : v;       cix = sw ? ti : cix;
                }
            }
        }
        // butterfly merge across the 4 parts (adjacent lanes)
        #pragma unroll
        for (int s = 1; s <= 2; s <<= 1) {
            float ov[4]; int oi[4];
            #pragma unroll
            for (int t = 0; t < 4; ++t) {
                ov[t] = __shfl_xor(bs4[t], s);
                oi[t] = __shfl_xor(bi4[t], s);
            }
            float rv[4]; int ri[4]; int pa = 0, pb = 0;
            #pragma unroll
            for (int t = 0; t < 4; ++t) {
                float va = sel4f(bs4, pa), vb = sel4f(ov, pb);
                bool ta = (va >= vb);
                rv[t] = ta ? va : vb;
                ri[t] = ta ? sel4i(bi4, pa) : sel4i(oi, pb);
                pa += ta ? 1 : 0; pb += ta ? 0 : 1;
            }
            #pragma unroll
            for (int t = 0; t < 4; ++t) { bs4[t] = rv[t]; bi4[t] = ri[t]; }
        }
        if (part == 0) {
            int grow = bm * BM + half * 64 + row4;
            *(float4*)(cand_s + (size_t)grow * NCAND + bn * 4) =
                make_float4(bs4[0], bs4[1], bs4[2], bs4[3]);
            *(int4*)(cand_i + (size_t)grow * NCAND + bn * 4) =
                make_int4(bi4[0], bi4[1], bi4[2], bi4[3]);
        }
    }
}

// ---------------- per-row merge of NCAND candidates -> top-K1 indices ----------------
__global__ __launch_bounds__(256) void merge_cands(const float* __restrict__ cand_s,
                                                   const int* __restrict__ cand_i,
                                                   int* __restrict__ sel_g) {
    __shared__ float Ms[256 * K1];
    __shared__ int   Mi[256 * K1];
    const int row = blockIdx.x, tid = threadIdx.x;
    const float* s = cand_s + (size_t)row * NCAND;
    const int*   x = cand_i + (size_t)row * NCAND;

    float ls[KTH]; int li[KTH];
    #pragma unroll
    for (int t = 0; t < KTH; ++t) { ls[t] = -2.f; li[t] = 0; }
    #pragma unroll
    for (int it = 0; it < NCAND / 256; ++it) {
        int j = tid + it * 256;
        float v = s[j];
        if (v > ls[KTH - 1]) {
            float cv = v; int ci = x[j];
            #pragma unroll
            for (int t = 0; t < KTH; ++t) {
                bool sw = cv > ls[t];
                float ts = ls[t]; int ti = li[t];
                ls[t] = sw ? cv : ts; li[t] = sw ? ci : ti;
                cv = sw ? ts : cv;   ci = sw ? ti : ci;
            }
        }
    }
    #pragma unroll
    for (int t = 0; t < KTH; ++t) { Ms[tid * K1 + t] = ls[t]; Mi[tid * K1 + t] = li[t]; }
    #pragma unroll
    for (int t = KTH; t < K1; ++t) { Ms[tid * K1 + t] = -3.f; Mi[tid * K1 + t] = 0; }
    __syncthreads();

    #pragma unroll
    for (int lev = 0; lev < 8; ++lev) {
        int stride = 1 << lev;
        if ((tid & (2 * stride - 1)) == 0) {
            int ia = tid * K1, ib = (tid + stride) * K1;
            float rs[K1]; int ri[K1];
            int pa = 0, pb = 0;
            #pragma unroll
            for (int t = 0; t < K1; ++t) {
                float va = Ms[ia + pa], vb = Ms[ib + pb];
                bool ta = (va >= vb);
                rs[t] = ta ? va : vb;
                ri[t] = ta ? Mi[ia + pa] : Mi[ib + pb];
                pa += ta ? 1 : 0; pb += ta ? 0 : 1;
            }
            #pragma unroll
            for (int t = 0; t < K1; ++t) { Ms[ia + t] = rs[t]; Mi[ia + t] = ri[t]; }
        }
        __syncthreads();
    }
    if (tid < K1) sel_g[(size_t)row * K1 + tid] = Mi[tid];
}

// ---------------- fp64 rescoring of K2 candidates + outputs ----------------
__global__ __launch_bounds__(256) void refine_out(const float* __restrict__ expd,
                                                  const float* __restrict__ pat,
                                                  const float* __restrict__ so3,
                                                  const int* __restrict__ sel_g,
                                                  float* __restrict__ out) {
    __shared__ double qc[N_PIX];
    __shared__ double pd[4], pd2[4], pd3[4];
    __shared__ int    sel[K2];
    __shared__ double cosv[K2];
    const int row = blockIdx.x, tid = threadIdx.x;
    const float* x = expd + (size_t)row * N_PIX;

    double s1 = 0.0;
    for (int j = tid; j < N_PIX; j += 256) s1 += (double)x[j];
    #pragma unroll
    for (int o = 32; o > 0; o >>= 1) s1 += __shfl_down(s1, o);
    if ((tid & 63) == 0) pd[tid >> 6] = s1;
    __syncthreads();
    const double mean = (pd[0] + pd[1] + pd[2] + pd[3]) * (1.0 / N_PIX);

    double s2 = 0.0, sc = 0.0;
    for (int j = tid; j < N_PIX; j += 256) {
        double c = (double)x[j] - mean;
        qc[j] = c; s2 += c * c; sc += c;
    }
    #pragma unroll
    for (int o = 32; o > 0; o >>= 1) { s2 += __shfl_down(s2, o); sc += __shfl_down(sc, o); }
    if ((tid & 63) == 0) { pd2[tid >> 6] = s2; pd3[tid >> 6] = sc; }
    if (tid < K2) sel[tid] = sel_g[(size_t)row * K2 + tid];
    __syncthreads();
    const double sumsq = pd2[0] + pd2[1] + pd2[2] + pd2[3];
    const double sqc   = pd3[0] + pd3[1] + pd3[2] + pd3[3];
    const double invq  = 1.0 / sqrt(sumsq);

    // fp64 exact cos for each selected candidate: 16 threads per candidate
    const int c  = tid >> 4;
    const int sl = tid & 15;
    const int di = sel[c];
    const float* p = pat + (size_t)di * N_PIX;
    double sp = 0.0, spp = 0.0, sqp = 0.0;
    for (int j = sl; j < N_PIX; j += 16) {
        double pv = (double)p[j];
        sp += pv; spp += pv * pv; sqp += qc[j] * pv;
    }
    #pragma unroll
    for (int o = 8; o > 0; o >>= 1) {
        sp  += __shfl_down(sp,  o, 16);
        spp += __shfl_down(spp, o, 16);
        sqp += __shfl_down(sqp, o, 16);
    }
    if (sl == 0) {
        double mp   = sp * (1.0 / N_PIX);
        double varp = spp - sp * sp * (1.0 / N_PIX);
        double invd = 1.0 / sqrt(varp);
        cosv[c] = (sqp - mp * sqc) * invq * invd;
    }
    __syncthreads();

    if (tid == 0) {
        double cv[K2]; int ci[K2];
        for (int t = 0; t < K2; ++t) { cv[t] = cosv[t]; ci[t] = sel[t]; }
        for (int a = 1; a < K2; ++a) {
            double kv = cv[a]; int ki = ci[a];
            int b = a - 1;
            while (b >= 0 && (cv[b] < kv || (cv[b] == kv && ci[b] > ki))) {
                cv[b + 1] = cv[b]; ci[b + 1] = ci[b]; --b;
            }
            cv[b + 1] = kv; ci[b + 1] = ki;
        }
        float* oa = out;
        float* oi = out + (size_t)N_EXP * TOPK;
        float* oo = out + (size_t)2 * N_EXP * TOPK;
        for (int r = 0; r < TOPK; ++r) {
            double cc = cv[r];
            if (cc > 1.0) cc = 1.0;
            if (cc < -1.0) cc = -1.0;
            oa[(size_t)row * TOPK + r] = (float)acos(cc);
            oi[(size_t)row * TOPK + r] = (float)ci[r];
            int q4 = ci[r];
            #pragma unroll
            for (int t = 0; t < 4; ++t)
                oo[((size_t)row * TOPK + r) * 4 + t] = so3[(size_t)q4 * 4 + t];
        }
    }
}

extern "C" void kernel_launch(void* const* d_in, const int* in_sizes, int n_in,
                              void* d_out, int out_size, void* d_ws, size_t ws_size,
                              hipStream_t stream) {
    const float* expd = (const float*)d_in[0];
    const float* pat  = (const float*)d_in[1];
    const float* so3  = (const float*)d_in[2];
    float* out = (float*)d_out;
    char* ws = (char*)d_ws;

    const size_t QB = (size_t)N_EXP  * N_PIX * 2;      //   6.6 MB bf16 queries
    const size_t DB = (size_t)N_DICT * N_PIX * 2;      // 209.7 MB bf16 dict
    const size_t CB = (size_t)N_EXP  * NCAND * 4;      //  16.8 MB cand scores

    unsigned short* Qb = (unsigned short*)ws;
    unsigned short* Db = (unsigned short*)(ws + QB);
    float* cs  = (float*)(ws + QB + DB);
    int*   ci  = (int*)  (ws + QB + DB + CB);
    int*   sel = (int*)  (ws + QB + DB + 2 * CB);

    prep_rows<<<N_EXP, 256, 0, stream>>>(expd, Qb);
    prep_rows<<<N_DICT, 256, 0, stream>>>(pat, Db);
    gemm_topk<<<dim3(N_EXP / BM, N_DICT / BN), 256, 0, stream>>>(Qb, Db, cs, ci);
    merge_cands<<<N_EXP, 256, 0, stream>>>(cs, ci, sel);
    refine_out<<<N_EXP, 256, 0, stream>>>(expd, pat, so3, sel, out);
}

// Round 3
// 1488.311 us; speedup vs baseline: 1.3865x; 1.0372x over previous
//
#include <hip/hip_runtime.h>
#include <stdint.h>

#define N_EXP  2048
#define N_DICT 65536
#define N_PIX  1600
#define TOPK   10
#define K1     16     // merged candidate list per row
#define KTH    8      // per-thread top list in merge kernel
#define K2     16     // refine set size
#define NBLK   512    // N_DICT / BN
#define NCAND  (NBLK * 4)   // candidates per row from gemm epilogue

#define BM 128
#define BN 128
#define BK 64
#define KTILES (N_PIX / BK)   // 25

typedef __attribute__((ext_vector_type(8))) __bf16 bf16x8;
typedef __attribute__((ext_vector_type(4))) float  f32x4;

// float -> bf16 (RNE)
__device__ __forceinline__ unsigned short f2bf(float f) {
    unsigned int u = __float_as_uint(f);
    unsigned int r = (u + 0x7FFFu + ((u >> 16) & 1u)) >> 16;
    return (unsigned short)r;
}

__device__ __forceinline__ float sel4f(const float a[4], int p) {
    return p == 0 ? a[0] : (p == 1 ? a[1] : (p == 2 ? a[2] : a[3]));
}
__device__ __forceinline__ int sel4i(const int a[4], int p) {
    return p == 0 ? a[0] : (p == 1 ? a[1] : (p == 2 ? a[2] : a[3]));
}

__device__ __forceinline__ float blockReduceSumF(float v) {
    __shared__ float p[4];
    #pragma unroll
    for (int o = 32; o > 0; o >>= 1) v += __shfl_down(v, o);
    __syncthreads();
    if ((threadIdx.x & 63) == 0) p[threadIdx.x >> 6] = v;
    __syncthreads();
    return p[0] + p[1] + p[2] + p[3];
}

// ---------------- prep: mean-subtract + normalize -> bf16 ----------------
__global__ __launch_bounds__(256) void prep_rows(const float* __restrict__ in,
                                                 unsigned short* __restrict__ outb) {
    const int row = blockIdx.x;
    const int tid = threadIdx.x;
    const float* x = in + (size_t)row * N_PIX;
    float v[7];
    float s = 0.f;
    #pragma unroll
    for (int it = 0; it < 7; ++it) {
        int j = tid + it * 256;
        float t = (j < N_PIX) ? x[j] : 0.f;
        v[it] = t; s += t;
    }
    s = blockReduceSumF(s);
    const float mean = s * (1.0f / N_PIX);
    float ss = 0.f;
    #pragma unroll
    for (int it = 0; it < 7; ++it) {
        int j = tid + it * 256;
        float c = v[it] - mean;
        if (j < N_PIX) ss += c * c;
    }
    ss = blockReduceSumF(ss);
    const float rn = rsqrtf(ss);
    unsigned short* o = outb + (size_t)row * N_PIX;
    #pragma unroll
    for (int it = 0; it < 7; ++it) {
        int j = tid + it * 256;
        if (j < N_PIX) o[j] = f2bf((v[it] - mean) * rn);
    }
}

// ---- bf16 GEMM with fused per-row top-4 epilogue ----
// LDS layout is XOR-swizzled: element chunk kc (16B) of row r lives at
// byte r*128 + (kc ^ (r&7))*16. Staged via global_load_lds by permuting
// the per-lane global source chunk; read back conflict-free (2-way max).
__global__ __launch_bounds__(256) void gemm_topk(const unsigned short* __restrict__ A,
                                                 const unsigned short* __restrict__ B,
                                                 float* __restrict__ cand_s,
                                                 int* __restrict__ cand_i) {
    __shared__ __attribute__((aligned(16))) char smem[32768];
    unsigned short* As = (unsigned short*)smem;            // 16 KB: 128 x 64 bf16
    unsigned short* Bs = (unsigned short*)(smem + 16384);  // 16 KB: 128 x 64 bf16
    float*          Ss = (float*)smem;                     // epilogue reuse: 64 x 128 f32

    const int tid  = threadIdx.x;
    const int lane = tid & 63;
    const int w    = tid >> 6;
    const int wm   = w >> 1, wn = w & 1;

    // XCD-aware swizzle: the 16 bm-blocks of one bn stay on one XCD.
    const int id  = blockIdx.x;
    const int xcd = id & 7;
    const int j_  = id >> 3;            // 0..1023 per-XCD sequence
    const int bm  = j_ & 15;
    const int bn  = (j_ >> 4) * 8 + xcd;

    const unsigned short* Ag = A + (size_t)bm * BM * N_PIX;
    const unsigned short* Bg = B + (size_t)bn * BN * N_PIX;

    const int ldr = lane >> 3;                      // row within 8-row chunk (== r&7)
    const int ldc = (((lane & 7) ^ ldr) * 8);       // swizzled source col chunk
    const int m    = lane & 15;
    const int quad = lane >> 4;

    f32x4 acc[4][4];
    #pragma unroll
    for (int i = 0; i < 4; ++i)
        #pragma unroll
        for (int j = 0; j < 4; ++j)
            acc[i][j] = (f32x4){0.f, 0.f, 0.f, 0.f};

    for (int kt = 0; kt < KTILES; ++kt) {
        const int k0 = kt * BK;
        #pragma unroll
        for (int t = 0; t < 4; ++t) {
            int r = w * 32 + t * 8 + ldr;
            __builtin_amdgcn_global_load_lds(
                (const __attribute__((address_space(1))) void*)(const void*)(Ag + (size_t)r * N_PIX + k0 + ldc),
                (__attribute__((address_space(3))) void*)(void*)((char*)As + (w * 4 + t) * 1024),
                16, 0, 0);
            __builtin_amdgcn_global_load_lds(
                (const __attribute__((address_space(1))) void*)(const void*)(Bg + (size_t)r * N_PIX + k0 + ldc),
                (__attribute__((address_space(3))) void*)(void*)((char*)Bs + (w * 4 + t) * 1024),
                16, 0, 0);
        }
        __syncthreads();
        #pragma unroll
        for (int ks = 0; ks < BK; ks += 32) {
            bf16x8 af[4], bfr[4];
            const int kc = (ks >> 3) + quad;        // 16B chunk index within row
            const int sw = (kc ^ (m & 7)) * 8;      // swizzled element offset
            #pragma unroll
            for (int i = 0; i < 4; ++i)
                af[i] = *(const bf16x8*)(&As[(wm * 64 + i * 16 + m) * BK + sw]);
            #pragma unroll
            for (int j = 0; j < 4; ++j)
                bfr[j] = *(const bf16x8*)(&Bs[(wn * 64 + j * 16 + m) * BK + sw]);
            #pragma unroll
            for (int i = 0; i < 4; ++i)
                #pragma unroll
                for (int j = 0; j < 4; ++j)
                    acc[i][j] = __builtin_amdgcn_mfma_f32_16x16x32_bf16(af[i], bfr[j], acc[i][j], 0, 0, 0);
        }
        __syncthreads();
    }

    // --- fused epilogue: per-row top-4 of this block's 128 cols ---
    // D layout: col = wn*64 + j*16 + m; row = wm*64 + i*16 + quad*4 + r
    const int row4 = tid >> 2;   // 0..63 (row within current half)
    const int part = tid & 3;    // quarter of the 128 cols

    #pragma unroll
    for (int half = 0; half < 2; ++half) {
        __syncthreads();
        if (wm == half) {
            #pragma unroll
            for (int i = 0; i < 4; ++i)
                #pragma unroll
                for (int r = 0; r < 4; ++r) {
                    int row = i * 16 + quad * 4 + r;       // 0..63
                    #pragma unroll
                    for (int j = 0; j < 4; ++j) {
                        int col = wn * 64 + j * 16 + m;
                        Ss[row * 128 + ((col + row) & 127)] = acc[i][j][r];
                    }
                }
        }
        __syncthreads();
        float bs4[4]; int bi4[4];
        bs4[0] = bs4[1] = bs4[2] = bs4[3] = -2.0f;
        bi4[0] = bi4[1] = bi4[2] = bi4[3] = 0;
        #pragma unroll
        for (int k = 0; k < 32; ++k) {
            int col = part * 32 + ((k + 8 * part) & 31);
            float v = Ss[row4 * 128 + ((col + row4) & 127)];
            if (v > bs4[3]) {
                int cix = bn * 128 + col;
                #pragma unroll
                for (int t = 0; t < 4; ++t) {
                    bool sw = v > bs4[t];
                    float ts = bs4[t]; int ti = bi4[t];
                    bs4[t] = sw ? v : ts;  bi4[t] = sw ? cix : ti;
                    v = sw ? ts : v;       cix = sw ? ti : cix;
                }
            }
        }
        // butterfly merge across the 4 parts (adjacent lanes)
        #pragma unroll
        for (int s = 1; s <= 2; s <<= 1) {
            float ov[4]; int oi[4];
            #pragma unroll
            for (int t = 0; t < 4; ++t) {
                ov[t] = __shfl_xor(bs4[t], s);
                oi[t] = __shfl_xor(bi4[t], s);
            }
            float rv[4]; int ri[4]; int pa = 0, pb = 0;
            #pragma unroll
            for (int t = 0; t < 4; ++t) {
                float va = sel4f(bs4, pa), vb = sel4f(ov, pb);
                bool ta = (va >= vb);
                rv[t] = ta ? va : vb;
                ri[t] = ta ? sel4i(bi4, pa) : sel4i(oi, pb);
                pa += ta ? 1 : 0; pb += ta ? 0 : 1;
            }
            #pragma unroll
            for (int t = 0; t < 4; ++t) { bs4[t] = rv[t]; bi4[t] = ri[t]; }
        }
        if (part == 0) {
            int grow = bm * BM + half * 64 + row4;
            *(float4*)(cand_s + (size_t)grow * NCAND + bn * 4) =
                make_float4(bs4[0], bs4[1], bs4[2], bs4[3]);
            *(int4*)(cand_i + (size_t)grow * NCAND + bn * 4) =
                make_int4(bi4[0], bi4[1], bi4[2], bi4[3]);
        }
    }
}

// ---------------- per-row merge of NCAND candidates -> top-K1 indices ----------------
__global__ __launch_bounds__(256) void merge_cands(const float* __restrict__ cand_s,
                                                   const int* __restrict__ cand_i,
                                                   int* __restrict__ sel_g) {
    __shared__ float Ms[256 * K1];
    __shared__ int   Mi[256 * K1];
    const int row = blockIdx.x, tid = threadIdx.x;
    const float* s = cand_s + (size_t)row * NCAND;
    const int*   x = cand_i + (size_t)row * NCAND;

    float ls[KTH]; int li[KTH];
    #pragma unroll
    for (int t = 0; t < KTH; ++t) { ls[t] = -2.f; li[t] = 0; }
    #pragma unroll
    for (int it = 0; it < NCAND / 256; ++it) {
        int j = tid + it * 256;
        float v = s[j];
        if (v > ls[KTH - 1]) {
            float cv = v; int ci = x[j];
            #pragma unroll
            for (int t = 0; t < KTH; ++t) {
                bool sw = cv > ls[t];
                float ts = ls[t]; int ti = li[t];
                ls[t] = sw ? cv : ts; li[t] = sw ? ci : ti;
                cv = sw ? ts : cv;   ci = sw ? ti : ci;
            }
        }
    }
    #pragma unroll
    for (int t = 0; t < KTH; ++t) { Ms[tid * K1 + t] = ls[t]; Mi[tid * K1 + t] = li[t]; }
    #pragma unroll
    for (int t = KTH; t < K1; ++t) { Ms[tid * K1 + t] = -3.f; Mi[tid * K1 + t] = 0; }
    __syncthreads();

    #pragma unroll
    for (int lev = 0; lev < 8; ++lev) {
        int stride = 1 << lev;
        if ((tid & (2 * stride - 1)) == 0) {
            int ia = tid * K1, ib = (tid + stride) * K1;
            float rs[K1]; int ri[K1];
            int pa = 0, pb = 0;
            #pragma unroll
            for (int t = 0; t < K1; ++t) {
                float va = Ms[ia + pa], vb = Ms[ib + pb];
                bool ta = (va >= vb);
                rs[t] = ta ? va : vb;
                ri[t] = ta ? Mi[ia + pa] : Mi[ib + pb];
                pa += ta ? 1 : 0; pb += ta ? 0 : 1;
            }
            #pragma unroll
            for (int t = 0; t < K1; ++t) { Ms[ia + t] = rs[t]; Mi[ia + t] = ri[t]; }
        }
        __syncthreads();
    }
    if (tid < K1) sel_g[(size_t)row * K1 + tid] = Mi[tid];
}

// ---------------- fp64 rescoring of K2 candidates + outputs ----------------
__global__ __launch_bounds__(256) void refine_out(const float* __restrict__ expd,
                                                  const float* __restrict__ pat,
                                                  const float* __restrict__ so3,
                                                  const int* __restrict__ sel_g,
                                                  float* __restrict__ out) {
    __shared__ double qc[N_PIX];
    __shared__ double pd[4], pd2[4], pd3[4];
    __shared__ int    sel[K2];
    __shared__ double cosv[K2];
    const int row = blockIdx.x, tid = threadIdx.x;
    const float* x = expd + (size_t)row * N_PIX;

    double s1 = 0.0;
    for (int j = tid; j < N_PIX; j += 256) s1 += (double)x[j];
    #pragma unroll
    for (int o = 32; o > 0; o >>= 1) s1 += __shfl_down(s1, o);
    if ((tid & 63) == 0) pd[tid >> 6] = s1;
    __syncthreads();
    const double mean = (pd[0] + pd[1] + pd[2] + pd[3]) * (1.0 / N_PIX);

    double s2 = 0.0, sc = 0.0;
    for (int j = tid; j < N_PIX; j += 256) {
        double c = (double)x[j] - mean;
        qc[j] = c; s2 += c * c; sc += c;
    }
    #pragma unroll
    for (int o = 32; o > 0; o >>= 1) { s2 += __shfl_down(s2, o); sc += __shfl_down(sc, o); }
    if ((tid & 63) == 0) { pd2[tid >> 6] = s2; pd3[tid >> 6] = sc; }
    if (tid < K2) sel[tid] = sel_g[(size_t)row * K2 + tid];
    __syncthreads();
    const double sumsq = pd2[0] + pd2[1] + pd2[2] + pd2[3];
    const double sqc   = pd3[0] + pd3[1] + pd3[2] + pd3[3];
    const double invq  = 1.0 / sqrt(sumsq);

    // fp64 exact cos for each selected candidate: 16 threads per candidate
    const int c  = tid >> 4;
    const int sl = tid & 15;
    const int di = sel[c];
    const float* p = pat + (size_t)di * N_PIX;
    double sp = 0.0, spp = 0.0, sqp = 0.0;
    for (int j = sl; j < N_PIX; j += 16) {
        double pv = (double)p[j];
        sp += pv; spp += pv * pv; sqp += qc[j] * pv;
    }
    #pragma unroll
    for (int o = 8; o > 0; o >>= 1) {
        sp  += __shfl_down(sp,  o, 16);
        spp += __shfl_down(spp, o, 16);
        sqp += __shfl_down(sqp, o, 16);
    }
    if (sl == 0) {
        double mp   = sp * (1.0 / N_PIX);
        double varp = spp - sp * sp * (1.0 / N_PIX);
        double invd = 1.0 / sqrt(varp);
        cosv[c] = (sqp - mp * sqc) * invq * invd;
    }
    __syncthreads();

    if (tid == 0) {
        double cv[K2]; int ci[K2];
        for (int t = 0; t < K2; ++t) { cv[t] = cosv[t]; ci[t] = sel[t]; }
        for (int a = 1; a < K2; ++a) {
            double kv = cv[a]; int ki = ci[a];
            int b = a - 1;
            while (b >= 0 && (cv[b] < kv || (cv[b] == kv && ci[b] > ki))) {
                cv[b + 1] = cv[b]; ci[b + 1] = ci[b]; --b;
            }
            cv[b + 1] = kv; ci[b + 1] = ki;
        }
        float* oa = out;
        float* oi = out + (size_t)N_EXP * TOPK;
        float* oo = out + (size_t)2 * N_EXP * TOPK;
        for (int r = 0; r < TOPK; ++r) {
            double cc = cv[r];
            if (cc > 1.0) cc = 1.0;
            if (cc < -1.0) cc = -1.0;
            oa[(size_t)row * TOPK + r] = (float)acos(cc);
            oi[(size_t)row * TOPK + r] = (float)ci[r];
            int q4 = ci[r];
            #pragma unroll
            for (int t = 0; t < 4; ++t)
                oo[((size_t)row * TOPK + r) * 4 + t] = so3[(size_t)q4 * 4 + t];
        }
    }
}

extern "C" void kernel_launch(void* const* d_in, const int* in_sizes, int n_in,
                              void* d_out, int out_size, void* d_ws, size_t ws_size,
                              hipStream_t stream) {
    const float* expd = (const float*)d_in[0];
    const float* pat  = (const float*)d_in[1];
    const float* so3  = (const float*)d_in[2];
    float* out = (float*)d_out;
    char* ws = (char*)d_ws;

    const size_t QB = (size_t)N_EXP  * N_PIX * 2;      //   6.6 MB bf16 queries
    const size_t DB = (size_t)N_DICT * N_PIX * 2;      // 209.7 MB bf16 dict
    const size_t CB = (size_t)N_EXP  * NCAND * 4;      //  16.8 MB cand scores

    unsigned short* Qb = (unsigned short*)ws;
    unsigned short* Db = (unsigned short*)(ws + QB);
    float* cs  = (float*)(ws + QB + DB);
    int*   ci  = (int*)  (ws + QB + DB + CB);
    int*   sel = (int*)  (ws + QB + DB + 2 * CB);

    prep_rows<<<N_EXP, 256, 0, stream>>>(expd, Qb);
    prep_rows<<<N_DICT, 256, 0, stream>>>(pat, Db);
    gemm_topk<<<(N_EXP / BM) * (N_DICT / BN), 256, 0, stream>>>(Qb, Db, cs, ci);
    merge_cands<<<N_EXP, 256, 0, stream>>>(cs, ci, sel);
    refine_out<<<N_EXP, 256, 0, stream>>>(expd, pat, so3, sel, out);
}